// Round 2
// baseline (1239.937 us; speedup 1.0000x reference)
//
#include <hip/hip_runtime.h>

#define E_DIM 2048
#define SEQ 2048
#define BATCH 2
#define NH 16
#define HD 128
#define PD 8192
#define M_ROWS 4096            // BATCH*SEQ
#define QKV_N 6144             // 3*E_DIM

typedef __attribute__((ext_vector_type(8))) short bf16x8;
typedef __attribute__((ext_vector_type(4))) float f32x4;

__device__ __forceinline__ unsigned short f2bf(float f) {
  unsigned u = __float_as_uint(f);
  u += 0x7fffu + ((u >> 16) & 1u);
  return (unsigned short)(u >> 16);
}

__device__ __forceinline__ float gelu_f(float x) {
  const float c = 0.7978845608028654f;  // sqrt(2/pi), jax approximate=True
  return 0.5f * x * (1.0f + tanhf(c * (x + 0.044715f * x * x * x)));
}

// async global->LDS, 16B per lane; LDS dest is wave-uniform base + lane*16
#define GLD16(gsrc, ldst) __builtin_amdgcn_global_load_lds( \
    (const __attribute__((address_space(1))) void*)(gsrc),  \
    (__attribute__((address_space(3))) void*)(ldst), 16, 0, 0)

// ---------------------------------------------------------------------------
// LayerNorm: fp32 [rows][2048] -> bf16, applies weight/bias. 1 block per row.
// ---------------------------------------------------------------------------
__global__ __launch_bounds__(256) void ln_kernel(const float* __restrict__ x,
                                                 const float* __restrict__ w,
                                                 const float* __restrict__ b,
                                                 unsigned short* __restrict__ out) {
  const int row = blockIdx.x;
  const int tid = threadIdx.x;
  const float* xr = x + (size_t)row * E_DIM;
  float4 v0 = *(const float4*)(xr + tid * 8);
  float4 v1 = *(const float4*)(xr + tid * 8 + 4);
  float s = v0.x + v0.y + v0.z + v0.w + v1.x + v1.y + v1.z + v1.w;
  float q = v0.x * v0.x + v0.y * v0.y + v0.z * v0.z + v0.w * v0.w +
            v1.x * v1.x + v1.y * v1.y + v1.z * v1.z + v1.w * v1.w;
#pragma unroll
  for (int o = 32; o; o >>= 1) { s += __shfl_xor(s, o); q += __shfl_xor(q, o); }
  __shared__ float ls[8];
  const int lane = tid & 63, wv = tid >> 6;
  if (lane == 0) { ls[wv] = s; ls[4 + wv] = q; }
  __syncthreads();
  s = ls[0] + ls[1] + ls[2] + ls[3];
  q = ls[4] + ls[5] + ls[6] + ls[7];
  const float mu = s * (1.0f / E_DIM);
  const float var = q * (1.0f / E_DIM) - mu * mu;
  const float rstd = rsqrtf(var + 1e-5f);
  float4 w0 = *(const float4*)(w + tid * 8);
  float4 w1 = *(const float4*)(w + tid * 8 + 4);
  float4 b0 = *(const float4*)(b + tid * 8);
  float4 b1 = *(const float4*)(b + tid * 8 + 4);
  ushort4 o0, o1;
  o0.x = f2bf((v0.x - mu) * rstd * w0.x + b0.x);
  o0.y = f2bf((v0.y - mu) * rstd * w0.y + b0.y);
  o0.z = f2bf((v0.z - mu) * rstd * w0.z + b0.z);
  o0.w = f2bf((v0.w - mu) * rstd * w0.w + b0.w);
  o1.x = f2bf((v1.x - mu) * rstd * w1.x + b1.x);
  o1.y = f2bf((v1.y - mu) * rstd * w1.y + b1.y);
  o1.z = f2bf((v1.z - mu) * rstd * w1.z + b1.z);
  o1.w = f2bf((v1.w - mu) * rstd * w1.w + b1.w);
  *(ushort4*)(out + (size_t)row * E_DIM + tid * 8) = o0;
  *(ushort4*)(out + (size_t)row * E_DIM + tid * 8 + 4) = o1;
}

// ---------------------------------------------------------------------------
// Transpose-convert: fp32 in[K][N] -> bf16 out[N][K].  64x64 tiles.
// ---------------------------------------------------------------------------
__global__ __launch_bounds__(256) void tconv_kernel(const float* __restrict__ in,
                                                    unsigned short* __restrict__ out,
                                                    int K, int N) {
  __shared__ float t[64][65];
  const int bn = blockIdx.x, bk = blockIdx.y;
  const int tid = threadIdx.x;
  const int c4 = (tid & 15) * 4;
  const int r0 = tid >> 4;
#pragma unroll
  for (int p = 0; p < 4; ++p) {
    const int r = p * 16 + r0;
    const float4 v = *(const float4*)(in + (size_t)(bk * 64 + r) * N + bn * 64 + c4);
    t[r][c4] = v.x; t[r][c4 + 1] = v.y; t[r][c4 + 2] = v.z; t[r][c4 + 3] = v.w;
  }
  __syncthreads();
#pragma unroll
  for (int p = 0; p < 4; ++p) {
    const int rn = p * 16 + r0;
    ushort4 o;
    o.x = f2bf(t[c4][rn]);     o.y = f2bf(t[c4 + 1][rn]);
    o.z = f2bf(t[c4 + 2][rn]); o.w = f2bf(t[c4 + 3][rn]);
    *(ushort4*)(out + (size_t)(bn * 64 + rn) * K + bk * 64 + c4) = o;
  }
}

__global__ void concat3_kernel(const float* __restrict__ a, const float* __restrict__ b,
                               const float* __restrict__ c, float* __restrict__ o) {
  int i = blockIdx.x * 256 + threadIdx.x;
  if (i < E_DIM) { o[i] = a[i]; o[E_DIM + i] = b[i]; o[2 * E_DIM + i] = c[i]; }
}

// ---------------------------------------------------------------------------
// GEMM: C[M,N] = A[M,K](bf16) @ Bt[N,K]^T(bf16) + bias (+res) (+gelu)
// m97 structure: 128x128 tile, BK=32, 4 waves (2x2), global_load_lds w=16.
// ---------------------------------------------------------------------------
template <int ACT, int RES, int OUTBF>
__global__ __launch_bounds__(256) void gemm_kernel(
    const unsigned short* __restrict__ A, const unsigned short* __restrict__ Bt,
    const float* __restrict__ bias, const float* __restrict__ res,
    void* __restrict__ Cout, int M, int N, int K) {
  __shared__ unsigned short lsA[128 * 32];
  __shared__ unsigned short lsB[128 * 32];
  const int tid = threadIdx.x;
  const int lane = tid & 63;
  const int w = tid >> 6;
  const int wr = w >> 1, wc = w & 1;
  const int bc = blockIdx.x, br = blockIdx.y;
  f32x4 acc[4][4] = {};
  const int nk = K >> 5;
  const int srow = lane >> 2;           // row-in-issue (16 rows of 64B)
  const int sch = lane & 3;             // 16B chunk in row
  const unsigned short* Abase = A + ((size_t)br * 128) * K + sch * 8;
  const unsigned short* Bbase = Bt + ((size_t)bc * 128) * K + sch * 8;

  for (int kt = 0; kt < nk; ++kt) {
    __syncthreads();                     // prev-iter LDS reads done
    const int kof = kt * 32;
#pragma unroll
    for (int i = 0; i < 2; ++i) {
      const int rowA = (i * 4 + w) * 16 + srow;
      GLD16(Abase + (size_t)rowA * K + kof, (char*)lsA + (i * 4 + w) * 1024);
      GLD16(Bbase + (size_t)rowA * K + kof, (char*)lsB + (i * 4 + w) * 1024);
    }
    __syncthreads();                     // staging complete (vmcnt drained)
    bf16x8 af[4], bfr[4];
#pragma unroll
    for (int mi = 0; mi < 4; ++mi) {
      const int rl = wr * 64 + mi * 16 + (lane & 15);
      af[mi] = *(const bf16x8*)(lsA + rl * 32 + (lane >> 4) * 8);
    }
#pragma unroll
    for (int ni = 0; ni < 4; ++ni) {
      const int rl = wc * 64 + ni * 16 + (lane & 15);
      bfr[ni] = *(const bf16x8*)(lsB + rl * 32 + (lane >> 4) * 8);
    }
#pragma unroll
    for (int mi = 0; mi < 4; ++mi)
#pragma unroll
      for (int ni = 0; ni < 4; ++ni)
        acc[mi][ni] = __builtin_amdgcn_mfma_f32_16x16x32_bf16(af[mi], bfr[ni], acc[mi][ni], 0, 0, 0);
  }

#pragma unroll
  for (int ni = 0; ni < 4; ++ni) {
    const int col = bc * 128 + wc * 64 + ni * 16 + (lane & 15);
    const float bv = bias[col];
#pragma unroll
    for (int mi = 0; mi < 4; ++mi) {
      const int row0 = br * 128 + wr * 64 + mi * 16 + (lane >> 4) * 4;
#pragma unroll
      for (int r = 0; r < 4; ++r) {
        const size_t idx = (size_t)(row0 + r) * N + col;
        float v = acc[mi][ni][r] + bv;
        if (RES) v += res[idx];
        if (ACT) v = gelu_f(v);
        if (OUTBF) ((unsigned short*)Cout)[idx] = f2bf(v);
        else       ((float*)Cout)[idx] = v;
      }
    }
  }
}

// ---------------------------------------------------------------------------
// Causal flash attention. qkv bf16 [4096][6144] (Q|K|V, head-major cols).
// Block: 1 (b,h), 64 Q rows (16/wave). KV tiles of 64. out bf16 [4096][2048].
// ---------------------------------------------------------------------------
__global__ __launch_bounds__(256) void attn_kernel(const unsigned short* __restrict__ qkv,
                                                   unsigned short* __restrict__ out) {
  __shared__ unsigned short lsK[64 * 128];   // [key][d], chunk ^= (key&7)
  __shared__ unsigned short lsV[128 * 64];   // Vt [d][key], chunk ^= (d&7)^((d>>3)&7)
  __shared__ unsigned short lsP[4 * 1024];   // per-wave P [16][64], chunk ^= (qrow&7)
  const int tid = threadIdx.x, lane = tid & 63, w = tid >> 6;
  const int qt = blockIdx.x, bh = blockIdx.y;
  const int b = bh >> 4, h = bh & 15;
  const int q0 = qt * 64;
  const size_t base = (size_t)b * SEQ * QKV_N + h * HD;

  bf16x8 qf[4];
  {
    const unsigned short* qp =
        qkv + base + (size_t)(q0 + w * 16 + (lane & 15)) * QKV_N + (lane >> 4) * 8;
#pragma unroll
    for (int kk = 0; kk < 4; ++kk) qf[kk] = *(const bf16x8*)(qp + kk * 32);
  }
  f32x4 o_acc[8] = {};
  float m_r[4] = {-INFINITY, -INFINITY, -INFINITY, -INFINITY};
  float l_r[4] = {0.f, 0.f, 0.f, 0.f};
  const float scale = 0.08838834764831845f;  // 1/sqrt(128)
  char* lsPw = (char*)(lsP + w * 1024);
  const int vdc = tid & 15, vkr = tid >> 4;

  const int nt = qt + 1;
  for (int kt = 0; kt < nt; ++kt) {
    const int k0 = kt * 64;
    __syncthreads();                     // prev-iter LDS reads done
    // ---- stage K (swizzle via pre-swizzled global source; LDS linear) ----
#pragma unroll
    for (int i = 0; i < 4; ++i) {
      const int row = (i * 4 + w) * 4 + (lane >> 4);
      const int cs = (lane & 15) ^ (row & 7);
      GLD16(qkv + base + E_DIM + (size_t)(k0 + row) * QKV_N + cs * 8,
            (char*)lsK + (i * 4 + w) * 1024);
    }
    // ---- stage V transposed + swizzled (reg-staged) ----
    {
      const unsigned short* gv =
          qkv + base + 2 * E_DIM + (size_t)(k0 + vkr * 4) * QKV_N + vdc * 8;
      bf16x8 vv0 = *(const bf16x8*)(gv);
      bf16x8 vv1 = *(const bf16x8*)(gv + QKV_N);
      bf16x8 vv2 = *(const bf16x8*)(gv + 2 * QKV_N);
      bf16x8 vv3 = *(const bf16x8*)(gv + 3 * QKV_N);
#pragma unroll
      for (int e = 0; e < 8; ++e) {
        const int d = vdc * 8 + e;
        const int swz = (d & 7) ^ ((d >> 3) & 7);
        {
          const int k = vkr * 4;
          const int off = d * 128 + (((k >> 3) ^ swz) << 4) + (k & 7) * 2;
          ushort2 t2; t2.x = (unsigned short)vv0[e]; t2.y = (unsigned short)vv1[e];
          *(ushort2*)((char*)lsV + off) = t2;
        }
        {
          const int k = vkr * 4 + 2;
          const int off = d * 128 + (((k >> 3) ^ swz) << 4) + (k & 7) * 2;
          ushort2 t2; t2.x = (unsigned short)vv2[e]; t2.y = (unsigned short)vv3[e];
          *(ushort2*)((char*)lsV + off) = t2;
        }
      }
    }
    __syncthreads();                     // staging complete
    // ---- QK^T : S[16q x 64k] per wave ----
    f32x4 sacc[4] = {};
#pragma unroll
    for (int kk = 0; kk < 4; ++kk) {
#pragma unroll
      for (int n = 0; n < 4; ++n) {
        const int row = n * 16 + (lane & 15);
        const int ch = (kk * 4 + (lane >> 4)) ^ (row & 7);
        bf16x8 kf = *(const bf16x8*)((const char*)lsK + row * 256 + ch * 16);
        sacc[n] = __builtin_amdgcn_mfma_f32_16x16x32_bf16(qf[kk], kf, sacc[n], 0, 0, 0);
      }
    }
    // ---- online softmax (rows r=0..3 per lane) ----
    const bool diag = (kt == nt - 1);
    float p[4][4];
#pragma unroll
    for (int r = 0; r < 4; ++r) {
      float sv[4];
#pragma unroll
      for (int n = 0; n < 4; ++n) {
        float t = sacc[n][r] * scale;
        if (diag && (n * 16 + (lane & 15)) > (w * 16 + (lane >> 4) * 4 + r)) t = -INFINITY;
        sv[n] = t;
      }
      float tm = fmaxf(fmaxf(sv[0], sv[1]), fmaxf(sv[2], sv[3]));
      tm = fmaxf(tm, __shfl_xor(tm, 1));
      tm = fmaxf(tm, __shfl_xor(tm, 2));
      tm = fmaxf(tm, __shfl_xor(tm, 4));
      tm = fmaxf(tm, __shfl_xor(tm, 8));
      const float mn = fmaxf(m_r[r], tm);
      const float corr = expf(m_r[r] - mn);   // exp(-inf)=0 on first tile
      float ps = 0.f;
#pragma unroll
      for (int n = 0; n < 4; ++n) { p[n][r] = expf(sv[n] - mn); ps += p[n][r]; }
      ps += __shfl_xor(ps, 1); ps += __shfl_xor(ps, 2);
      ps += __shfl_xor(ps, 4); ps += __shfl_xor(ps, 8);
      l_r[r] = l_r[r] * corr + ps;
      m_r[r] = mn;
#pragma unroll
      for (int dn = 0; dn < 8; ++dn) o_acc[dn][r] *= corr;
    }
    // ---- P -> LDS (bf16, swizzled) ----
#pragma unroll
    for (int n = 0; n < 4; ++n)
#pragma unroll
      for (int r = 0; r < 4; ++r) {
        const int prow = (lane >> 4) * 4 + r;
        const int pcol = n * 16 + (lane & 15);
        const int off = prow * 128 + ((((pcol >> 3) ^ (prow & 7))) << 4) + (pcol & 7) * 2;
        *(unsigned short*)(lsPw + off) = f2bf(p[n][r]);
      }
    // ---- PV : O[16q x 128d] += P @ V ----
    bf16x8 pa[2];
#pragma unroll
    for (int ks = 0; ks < 2; ++ks) {
      const int prow = lane & 15;
      const int ch = (ks * 4 + (lane >> 4)) ^ (prow & 7);
      pa[ks] = *(const bf16x8*)(lsPw + prow * 128 + ch * 16);
    }
#pragma unroll
    for (int dn = 0; dn < 8; ++dn)
#pragma unroll
      for (int ks = 0; ks < 2; ++ks) {
        const int d = dn * 16 + (lane & 15);
        const int ch = (ks * 4 + (lane >> 4)) ^ (d & 7) ^ ((d >> 3) & 7);
        bf16x8 vf = *(const bf16x8*)((const char*)lsV + d * 128 + ch * 16);
        o_acc[dn] = __builtin_amdgcn_mfma_f32_16x16x32_bf16(pa[ks], vf, o_acc[dn], 0, 0, 0);
      }
  }
  // ---- epilogue ----
#pragma unroll
  for (int r = 0; r < 4; ++r) {
    const float inv = 1.0f / l_r[r];
    const int row = q0 + w * 16 + (lane >> 4) * 4 + r;
    unsigned short* op = out + ((size_t)(b * SEQ + row)) * E_DIM + h * HD + (lane & 15);
#pragma unroll
    for (int dn = 0; dn < 8; ++dn) op[dn * 16] = f2bf(o_acc[dn][r] * inv);
  }
}

// ---------------------------------------------------------------------------
extern "C" void kernel_launch(void* const* d_in, const int* in_sizes, int n_in,
                              void* d_out, int out_size, void* d_ws, size_t ws_size,
                              hipStream_t stream) {
  const float* x    = (const float*)d_in[0];
  const float* ln1w = (const float*)d_in[1];
  const float* ln1b = (const float*)d_in[2];
  const float* ln2w = (const float*)d_in[3];
  const float* ln2b = (const float*)d_in[4];
  const float* wq   = (const float*)d_in[5];
  const float* bq   = (const float*)d_in[6];
  const float* wk   = (const float*)d_in[7];
  const float* bk   = (const float*)d_in[8];
  const float* wv   = (const float*)d_in[9];
  const float* bv   = (const float*)d_in[10];
  const float* wo   = (const float*)d_in[11];
  const float* bo   = (const float*)d_in[12];
  const float* w1   = (const float*)d_in[13];
  const float* b1   = (const float*)d_in[14];
  const float* w2   = (const float*)d_in[15];
  const float* b2   = (const float*)d_in[16];
  (void)in_sizes; (void)n_in; (void)out_size; (void)ws_size;

  char* ws = (char*)d_ws;
  size_t off = 0;
  auto alloc = [&](size_t bytes) {
    char* p = ws + off;
    off += (bytes + 255) & ~(size_t)255;
    return p;
  };
  // persistent across the whole launch:
  unsigned short* wqkv_t = (unsigned short*)alloc((size_t)QKV_N * E_DIM * 2);  // 25.2 MB
  unsigned short* wo_t   = (unsigned short*)alloc((size_t)E_DIM * E_DIM * 2);  //  8.4 MB
  unsigned short* w1_t   = (unsigned short*)alloc((size_t)PD * E_DIM * 2);     // 33.6 MB
  unsigned short* w2_t   = (unsigned short*)alloc((size_t)E_DIM * PD * 2);     // 33.6 MB
  float*          qkvb   = (float*)alloc((size_t)QKV_N * 4);
  float*          hbuf   = (float*)alloc((size_t)M_ROWS * E_DIM * 4);          // 33.6 MB
  // aliased region A: xn[4096x2048 bf16] + qkv[4096x6144 bf16]  ==  g[4096x8192 bf16]
  unsigned short* xn     = (unsigned short*)alloc((size_t)M_ROWS * (E_DIM + QKV_N) * 2);
  unsigned short* qkv    = xn + (size_t)M_ROWS * E_DIM;
  unsigned short* g      = xn;   // reused after qkv's last read (attn kernel)
  // aliased region B: attn[4096x2048 bf16] reused as hn after O-proj reads it
  unsigned short* attn   = (unsigned short*)alloc((size_t)M_ROWS * E_DIM * 2); // 16.8 MB
  unsigned short* hn     = attn; // reused after O-proj
  // peak ws ≈ 218 MB

  // weights -> bf16, transposed to [N][K]
  tconv_kernel<<<dim3(E_DIM / 64, E_DIM / 64), 256, 0, stream>>>(wq, wqkv_t, E_DIM, E_DIM);
  tconv_kernel<<<dim3(E_DIM / 64, E_DIM / 64), 256, 0, stream>>>(wk, wqkv_t + (size_t)E_DIM * E_DIM, E_DIM, E_DIM);
  tconv_kernel<<<dim3(E_DIM / 64, E_DIM / 64), 256, 0, stream>>>(wv, wqkv_t + (size_t)2 * E_DIM * E_DIM, E_DIM, E_DIM);
  tconv_kernel<<<dim3(E_DIM / 64, E_DIM / 64), 256, 0, stream>>>(wo, wo_t, E_DIM, E_DIM);
  tconv_kernel<<<dim3(PD / 64, E_DIM / 64), 256, 0, stream>>>(w1, w1_t, E_DIM, PD);
  tconv_kernel<<<dim3(E_DIM / 64, PD / 64), 256, 0, stream>>>(w2, w2_t, PD, E_DIM);
  concat3_kernel<<<dim3(E_DIM / 256), 256, 0, stream>>>(bq, bk, bv, qkvb);

  // LN1 -> QKV GEMM -> attention
  ln_kernel<<<dim3(M_ROWS), 256, 0, stream>>>(x, ln1w, ln1b, xn);
  gemm_kernel<0, 0, 1><<<dim3(QKV_N / 128, M_ROWS / 128), 256, 0, stream>>>(
      xn, wqkv_t, qkvb, nullptr, qkv, M_ROWS, QKV_N, E_DIM);
  attn_kernel<<<dim3(SEQ / 64, BATCH * NH), 256, 0, stream>>>(qkv, attn);

  // O-proj + residual(x) -> h (fp32)
  gemm_kernel<0, 1, 0><<<dim3(E_DIM / 128, M_ROWS / 128), 256, 0, stream>>>(
      attn, wo_t, bo, x, hbuf, M_ROWS, E_DIM, E_DIM);
  // LN2 -> hn (overwrites attn buffer; attn is dead now)
  ln_kernel<<<dim3(M_ROWS), 256, 0, stream>>>(hbuf, ln2w, ln2b, hn);
  // MLP1 + gelu -> g (overwrites xn+qkv region; both dead now)
  gemm_kernel<1, 0, 1><<<dim3(PD / 128, M_ROWS / 128), 256, 0, stream>>>(
      hn, w1_t, b1, nullptr, g, M_ROWS, PD, E_DIM);
  // MLP2 + residual(h) -> out (fp32)
  gemm_kernel<0, 1, 0><<<dim3(E_DIM / 128, M_ROWS / 128), 256, 0, stream>>>(
      g, w2_t, b2, hbuf, (float*)d_out, M_ROWS, E_DIM, PD);
}

// Round 3
// 991.372 us; speedup vs baseline: 1.2507x; 1.2507x over previous
//
#include <hip/hip_runtime.h>

#define E_DIM 2048
#define SEQ 2048
#define BATCH 2
#define NH 16
#define HD 128
#define PD 8192
#define M_ROWS 4096            // BATCH*SEQ
#define QKV_N 6144             // 3*E_DIM
#define NQT 32                 // SEQ/64

typedef __attribute__((ext_vector_type(8))) short bf16x8;
typedef __attribute__((ext_vector_type(4))) float f32x4;

__device__ __forceinline__ unsigned short f2bf(float f) {
  unsigned u = __float_as_uint(f);
  u += 0x7fffu + ((u >> 16) & 1u);
  return (unsigned short)(u >> 16);
}

__device__ __forceinline__ float gelu_f(float x) {
  const float c = 0.7978845608028654f;  // sqrt(2/pi), jax approximate=True
  return 0.5f * x * (1.0f + tanhf(c * (x + 0.044715f * x * x * x)));
}

// async global->LDS, 16B per lane; LDS dest is wave-uniform base + lane*16
#define GLD16(gsrc, ldst) __builtin_amdgcn_global_load_lds( \
    (const __attribute__((address_space(1))) void*)(gsrc),  \
    (__attribute__((address_space(3))) void*)(ldst), 16, 0, 0)

// ---------------------------------------------------------------------------
// LayerNorm: fp32 [rows][2048] -> bf16, applies weight/bias. 1 block per row.
// ---------------------------------------------------------------------------
__global__ __launch_bounds__(256) void ln_kernel(const float* __restrict__ x,
                                                 const float* __restrict__ w,
                                                 const float* __restrict__ b,
                                                 unsigned short* __restrict__ out) {
  const int row = blockIdx.x;
  const int tid = threadIdx.x;
  const float* xr = x + (size_t)row * E_DIM;
  float4 v0 = *(const float4*)(xr + tid * 8);
  float4 v1 = *(const float4*)(xr + tid * 8 + 4);
  float s = v0.x + v0.y + v0.z + v0.w + v1.x + v1.y + v1.z + v1.w;
  float q = v0.x * v0.x + v0.y * v0.y + v0.z * v0.z + v0.w * v0.w +
            v1.x * v1.x + v1.y * v1.y + v1.z * v1.z + v1.w * v1.w;
#pragma unroll
  for (int o = 32; o; o >>= 1) { s += __shfl_xor(s, o); q += __shfl_xor(q, o); }
  __shared__ float ls[8];
  const int lane = tid & 63, wv = tid >> 6;
  if (lane == 0) { ls[wv] = s; ls[4 + wv] = q; }
  __syncthreads();
  s = ls[0] + ls[1] + ls[2] + ls[3];
  q = ls[4] + ls[5] + ls[6] + ls[7];
  const float mu = s * (1.0f / E_DIM);
  const float var = q * (1.0f / E_DIM) - mu * mu;
  const float rstd = rsqrtf(var + 1e-5f);
  float4 w0 = *(const float4*)(w + tid * 8);
  float4 w1 = *(const float4*)(w + tid * 8 + 4);
  float4 b0 = *(const float4*)(b + tid * 8);
  float4 b1 = *(const float4*)(b + tid * 8 + 4);
  ushort4 o0, o1;
  o0.x = f2bf((v0.x - mu) * rstd * w0.x + b0.x);
  o0.y = f2bf((v0.y - mu) * rstd * w0.y + b0.y);
  o0.z = f2bf((v0.z - mu) * rstd * w0.z + b0.z);
  o0.w = f2bf((v0.w - mu) * rstd * w0.w + b0.w);
  o1.x = f2bf((v1.x - mu) * rstd * w1.x + b1.x);
  o1.y = f2bf((v1.y - mu) * rstd * w1.y + b1.y);
  o1.z = f2bf((v1.z - mu) * rstd * w1.z + b1.z);
  o1.w = f2bf((v1.w - mu) * rstd * w1.w + b1.w);
  *(ushort4*)(out + (size_t)row * E_DIM + tid * 8) = o0;
  *(ushort4*)(out + (size_t)row * E_DIM + tid * 8 + 4) = o1;
}

// ---------------------------------------------------------------------------
// Transpose-convert: fp32 in[K][N] -> bf16 out[N][K].  64x64 tiles.
// ---------------------------------------------------------------------------
__global__ __launch_bounds__(256) void tconv_kernel(const float* __restrict__ in,
                                                    unsigned short* __restrict__ out,
                                                    int K, int N) {
  __shared__ float t[64][65];
  const int bn = blockIdx.x, bk = blockIdx.y;
  const int tid = threadIdx.x;
  const int c4 = (tid & 15) * 4;
  const int r0 = tid >> 4;
#pragma unroll
  for (int p = 0; p < 4; ++p) {
    const int r = p * 16 + r0;
    const float4 v = *(const float4*)(in + (size_t)(bk * 64 + r) * N + bn * 64 + c4);
    t[r][c4] = v.x; t[r][c4 + 1] = v.y; t[r][c4 + 2] = v.z; t[r][c4 + 3] = v.w;
  }
  __syncthreads();
#pragma unroll
  for (int p = 0; p < 4; ++p) {
    const int rn = p * 16 + r0;
    ushort4 o;
    o.x = f2bf(t[c4][rn]);     o.y = f2bf(t[c4 + 1][rn]);
    o.z = f2bf(t[c4 + 2][rn]); o.w = f2bf(t[c4 + 3][rn]);
    *(ushort4*)(out + (size_t)(bn * 64 + rn) * K + bk * 64 + c4) = o;
  }
}

__global__ void concat3_kernel(const float* __restrict__ a, const float* __restrict__ b,
                               const float* __restrict__ c, float* __restrict__ o) {
  int i = blockIdx.x * 256 + threadIdx.x;
  if (i < E_DIM) { o[i] = a[i]; o[E_DIM + i] = b[i]; o[2 * E_DIM + i] = c[i]; }
}

// ---------------------------------------------------------------------------
// GEMM: C[M,N] = A[M,K](bf16) @ Bt[N,K]^T(bf16) + bias (+res) (+gelu)
// m97 structure: 128x128 tile, BK=32, 4 waves (2x2), global_load_lds w=16.
// ---------------------------------------------------------------------------
template <int ACT, int RES, int OUTBF>
__global__ __launch_bounds__(256) void gemm_kernel(
    const unsigned short* __restrict__ A, const unsigned short* __restrict__ Bt,
    const float* __restrict__ bias, const float* __restrict__ res,
    void* __restrict__ Cout, int M, int N, int K) {
  __shared__ unsigned short lsA[128 * 32];
  __shared__ unsigned short lsB[128 * 32];
  const int tid = threadIdx.x;
  const int lane = tid & 63;
  const int w = tid >> 6;
  const int wr = w >> 1, wc = w & 1;
  const int bc = blockIdx.x, br = blockIdx.y;
  f32x4 acc[4][4] = {};
  const int nk = K >> 5;
  const int srow = lane >> 2;           // row-in-issue (16 rows of 64B)
  const int sch = lane & 3;             // 16B chunk in row
  const unsigned short* Abase = A + ((size_t)br * 128) * K + sch * 8;
  const unsigned short* Bbase = Bt + ((size_t)bc * 128) * K + sch * 8;

  for (int kt = 0; kt < nk; ++kt) {
    __syncthreads();                     // prev-iter LDS reads done
    const int kof = kt * 32;
#pragma unroll
    for (int i = 0; i < 2; ++i) {
      const int rowA = (i * 4 + w) * 16 + srow;
      GLD16(Abase + (size_t)rowA * K + kof, (char*)lsA + (i * 4 + w) * 1024);
      GLD16(Bbase + (size_t)rowA * K + kof, (char*)lsB + (i * 4 + w) * 1024);
    }
    __syncthreads();                     // staging complete (vmcnt drained)
    bf16x8 af[4], bfr[4];
#pragma unroll
    for (int mi = 0; mi < 4; ++mi) {
      const int rl = wr * 64 + mi * 16 + (lane & 15);
      af[mi] = *(const bf16x8*)(lsA + rl * 32 + (lane >> 4) * 8);
    }
#pragma unroll
    for (int ni = 0; ni < 4; ++ni) {
      const int rl = wc * 64 + ni * 16 + (lane & 15);
      bfr[ni] = *(const bf16x8*)(lsB + rl * 32 + (lane >> 4) * 8);
    }
#pragma unroll
    for (int mi = 0; mi < 4; ++mi)
#pragma unroll
      for (int ni = 0; ni < 4; ++ni)
        acc[mi][ni] = __builtin_amdgcn_mfma_f32_16x16x32_bf16(af[mi], bfr[ni], acc[mi][ni], 0, 0, 0);
  }

#pragma unroll
  for (int ni = 0; ni < 4; ++ni) {
    const int col = bc * 128 + wc * 64 + ni * 16 + (lane & 15);
    const float bv = bias[col];
#pragma unroll
    for (int mi = 0; mi < 4; ++mi) {
      const int row0 = br * 128 + wr * 64 + mi * 16 + (lane >> 4) * 4;
#pragma unroll
      for (int r = 0; r < 4; ++r) {
        const size_t idx = (size_t)(row0 + r) * N + col;
        float v = acc[mi][ni][r] + bv;
        if (RES) v += res[idx];
        if (ACT) v = gelu_f(v);
        if (OUTBF) ((unsigned short*)Cout)[idx] = f2bf(v);
        else       ((float*)Cout)[idx] = v;
      }
    }
  }
}

// ---------------------------------------------------------------------------
// Causal flash attention, depth-1 pipelined. qkv bf16 [4096][6144] (Q|K|V).
// Block: 1 (b,h) x 2 paired q-tiles (qt, 31-qt) -> equal work (33 iters).
// 4 waves, 16 q-rows/wave. K double-buffered in LDS (GLD16, pre-swizzled
// source); V reg-staged early, ds_write late (async-STAGE split).
// ---------------------------------------------------------------------------
__global__ __launch_bounds__(256) void attn_kernel(const unsigned short* __restrict__ qkv,
                                                   unsigned short* __restrict__ out) {
  __shared__ unsigned short lsK[2][64 * 128];  // [key][d], chunk ^= (key&7)
  __shared__ unsigned short lsV[128 * 64];     // Vt [d][key], chunk ^= (d&7)^((d>>3)&7)
  __shared__ unsigned short lsP[4 * 1024];     // per-wave P [16][64], chunk ^= (qrow&7)
  const int tid = threadIdx.x, lane = tid & 63, w = tid >> 6;
  const int pair = blockIdx.x, bh = blockIdx.y;
  const int b = bh >> 4, h = bh & 15;
  const size_t base = (size_t)b * SEQ * QKV_N + h * HD;
  const float scale = 0.08838834764831845f;  // 1/sqrt(128)
  char* lsPw = (char*)(lsP + w * 1024);
  const int vdc = tid & 15, vkr = tid >> 4;

  for (int half = 0; half < 2; ++half) {
    const int qt = half ? (NQT - 1 - pair) : pair;
    const int q0 = qt * 64;
    const int nt = qt + 1;

    // Q fragments for this q-tile
    bf16x8 qf[4];
    {
      const unsigned short* qp =
          qkv + base + (size_t)(q0 + w * 16 + (lane & 15)) * QKV_N + (lane >> 4) * 8;
#pragma unroll
      for (int kk = 0; kk < 4; ++kk) qf[kk] = *(const bf16x8*)(qp + kk * 32);
    }
    f32x4 o_acc[8] = {};
    float m_r[4] = {-INFINITY, -INFINITY, -INFINITY, -INFINITY};
    float l_r[4] = {0.f, 0.f, 0.f, 0.f};
    bf16x8 vv0, vv1, vv2, vv3;

    // ---- prologue: K tile0 -> lsK[0] (async), V tile0 -> regs ----
    {
#pragma unroll
      for (int i = 0; i < 4; ++i) {
        const int row = (i * 4 + w) * 4 + (lane >> 4);
        const int cs = (lane & 15) ^ (row & 7);
        GLD16(qkv + base + E_DIM + (size_t)row * QKV_N + cs * 8,
              (char*)lsK[0] + (i * 4 + w) * 1024);
      }
      const unsigned short* gv = qkv + base + 2 * E_DIM + (size_t)(vkr * 4) * QKV_N + vdc * 8;
      vv0 = *(const bf16x8*)(gv);
      vv1 = *(const bf16x8*)(gv + QKV_N);
      vv2 = *(const bf16x8*)(gv + 2 * QKV_N);
      vv3 = *(const bf16x8*)(gv + 3 * QKV_N);
    }
    __syncthreads();   // K0 resident (vmcnt drained); prev-half LDS reads done
    // write V tile0 (transposed + swizzled)
#pragma unroll
    for (int e = 0; e < 8; ++e) {
      const int d = vdc * 8 + e;
      const int swz = (d & 7) ^ ((d >> 3) & 7);
      {
        const int k = vkr * 4;
        const int off = d * 128 + (((k >> 3) ^ swz) << 4) + (k & 7) * 2;
        ushort2 t2; t2.x = (unsigned short)vv0[e]; t2.y = (unsigned short)vv1[e];
        *(ushort2*)((char*)lsV + off) = t2;
      }
      {
        const int k = vkr * 4 + 2;
        const int off = d * 128 + (((k >> 3) ^ swz) << 4) + (k & 7) * 2;
        ushort2 t2; t2.x = (unsigned short)vv2[e]; t2.y = (unsigned short)vv3[e];
        *(ushort2*)((char*)lsV + off) = t2;
      }
    }

    for (int kt = 0; kt < nt; ++kt) {
      const int cur = kt & 1;
      const bool pf = (kt + 1 < nt);
      // ---- prefetch next tile: K -> lsK[cur^1] (async), V -> regs ----
      if (pf) {
        const int k0n = (kt + 1) * 64;
#pragma unroll
        for (int i = 0; i < 4; ++i) {
          const int row = (i * 4 + w) * 4 + (lane >> 4);
          const int cs = (lane & 15) ^ (row & 7);
          GLD16(qkv + base + E_DIM + (size_t)(k0n + row) * QKV_N + cs * 8,
                (char*)lsK[cur ^ 1] + (i * 4 + w) * 1024);
        }
        const unsigned short* gv =
            qkv + base + 2 * E_DIM + (size_t)(k0n + vkr * 4) * QKV_N + vdc * 8;
        vv0 = *(const bf16x8*)(gv);
        vv1 = *(const bf16x8*)(gv + QKV_N);
        vv2 = *(const bf16x8*)(gv + 2 * QKV_N);
        vv3 = *(const bf16x8*)(gv + 3 * QKV_N);
      }
      // ---- QK^T : S[16q x 64k] per wave, from lsK[cur] ----
      f32x4 sacc[4] = {};
#pragma unroll
      for (int kk = 0; kk < 4; ++kk) {
#pragma unroll
        for (int n = 0; n < 4; ++n) {
          const int row = n * 16 + (lane & 15);
          const int ch = (kk * 4 + (lane >> 4)) ^ (row & 7);
          bf16x8 kf = *(const bf16x8*)((const char*)lsK[cur] + row * 256 + ch * 16);
          sacc[n] = __builtin_amdgcn_mfma_f32_16x16x32_bf16(qf[kk], kf, sacc[n], 0, 0, 0);
        }
      }
      // ---- online softmax (rows r=0..3 per lane) ----
      const bool diag = (kt == nt - 1);
      float p[4][4];
#pragma unroll
      for (int r = 0; r < 4; ++r) {
        float sv[4];
#pragma unroll
        for (int n = 0; n < 4; ++n) {
          float t = sacc[n][r] * scale;
          if (diag && (n * 16 + (lane & 15)) > (w * 16 + (lane >> 4) * 4 + r)) t = -INFINITY;
          sv[n] = t;
        }
        float tm = fmaxf(fmaxf(sv[0], sv[1]), fmaxf(sv[2], sv[3]));
        tm = fmaxf(tm, __shfl_xor(tm, 1));
        tm = fmaxf(tm, __shfl_xor(tm, 2));
        tm = fmaxf(tm, __shfl_xor(tm, 4));
        tm = fmaxf(tm, __shfl_xor(tm, 8));
        const float mn = fmaxf(m_r[r], tm);
        const float corr = __expf(m_r[r] - mn);   // exp(-inf)=0 on first tile
        float ps = 0.f;
#pragma unroll
        for (int n = 0; n < 4; ++n) { p[n][r] = __expf(sv[n] - mn); ps += p[n][r]; }
        ps += __shfl_xor(ps, 1); ps += __shfl_xor(ps, 2);
        ps += __shfl_xor(ps, 4); ps += __shfl_xor(ps, 8);
        l_r[r] = l_r[r] * corr + ps;
        m_r[r] = mn;
#pragma unroll
        for (int dn = 0; dn < 8; ++dn) o_acc[dn][r] *= corr;
      }
      __syncthreads();   // B1: V(cur) writes visible to all waves; K-next drained
      // ---- P -> LDS (bf16, swizzled, per-wave region) ----
#pragma unroll
      for (int n = 0; n < 4; ++n)
#pragma unroll
        for (int r = 0; r < 4; ++r) {
          const int prow = (lane >> 4) * 4 + r;
          const int pcol = n * 16 + (lane & 15);
          const int off = prow * 128 + ((((pcol >> 3) ^ (prow & 7))) << 4) + (pcol & 7) * 2;
          *(unsigned short*)(lsPw + off) = f2bf(p[n][r]);
        }
      // ---- PV : O[16q x 128d] += P @ V ----
      bf16x8 pa[2];
#pragma unroll
      for (int ks = 0; ks < 2; ++ks) {
        const int prow = lane & 15;
        const int ch = (ks * 4 + (lane >> 4)) ^ (prow & 7);
        pa[ks] = *(const bf16x8*)(lsPw + prow * 128 + ch * 16);
      }
#pragma unroll
      for (int dn = 0; dn < 8; ++dn)
#pragma unroll
        for (int ks = 0; ks < 2; ++ks) {
          const int d = dn * 16 + (lane & 15);
          const int ch = (ks * 4 + (lane >> 4)) ^ (d & 7) ^ ((d >> 3) & 7);
          bf16x8 vf = *(const bf16x8*)((const char*)lsV + d * 128 + ch * 16);
          o_acc[dn] = __builtin_amdgcn_mfma_f32_16x16x32_bf16(pa[ks], vf, o_acc[dn], 0, 0, 0);
        }
      __syncthreads();   // B2: all waves done reading lsV -> safe to overwrite
      // ---- late V write for next tile (regs loaded at top of this iter) ----
      if (pf) {
#pragma unroll
        for (int e = 0; e < 8; ++e) {
          const int d = vdc * 8 + e;
          const int swz = (d & 7) ^ ((d >> 3) & 7);
          {
            const int k = vkr * 4;
            const int off = d * 128 + (((k >> 3) ^ swz) << 4) + (k & 7) * 2;
            ushort2 t2; t2.x = (unsigned short)vv0[e]; t2.y = (unsigned short)vv1[e];
            *(ushort2*)((char*)lsV + off) = t2;
          }
          {
            const int k = vkr * 4 + 2;
            const int off = d * 128 + (((k >> 3) ^ swz) << 4) + (k & 7) * 2;
            ushort2 t2; t2.x = (unsigned short)vv2[e]; t2.y = (unsigned short)vv3[e];
            *(ushort2*)((char*)lsV + off) = t2;
          }
        }
      }
    }
    // ---- epilogue for this q-tile ----
#pragma unroll
    for (int r = 0; r < 4; ++r) {
      const float inv = 1.0f / l_r[r];
      const int row = q0 + w * 16 + (lane >> 4) * 4 + r;
      unsigned short* op = out + ((size_t)(b * SEQ + row)) * E_DIM + h * HD + (lane & 15);
#pragma unroll
      for (int dn = 0; dn < 8; ++dn) op[dn * 16] = f2bf(o_acc[dn][r] * inv);
    }
  }
}

// ---------------------------------------------------------------------------
extern "C" void kernel_launch(void* const* d_in, const int* in_sizes, int n_in,
                              void* d_out, int out_size, void* d_ws, size_t ws_size,
                              hipStream_t stream) {
  const float* x    = (const float*)d_in[0];
  const float* ln1w = (const float*)d_in[1];
  const float* ln1b = (const float*)d_in[2];
  const float* ln2w = (const float*)d_in[3];
  const float* ln2b = (const float*)d_in[4];
  const float* wq   = (const float*)d_in[5];
  const float* bq   = (const float*)d_in[6];
  const float* wk   = (const float*)d_in[7];
  const float* bk   = (const float*)d_in[8];
  const float* wv   = (const float*)d_in[9];
  const float* bv   = (const float*)d_in[10];
  const float* wo   = (const float*)d_in[11];
  const float* bo   = (const float*)d_in[12];
  const float* w1   = (const float*)d_in[13];
  const float* b1   = (const float*)d_in[14];
  const float* w2   = (const float*)d_in[15];
  const float* b2   = (const float*)d_in[16];
  (void)in_sizes; (void)n_in; (void)out_size; (void)ws_size;

  char* ws = (char*)d_ws;
  size_t off = 0;
  auto alloc = [&](size_t bytes) {
    char* p = ws + off;
    off += (bytes + 255) & ~(size_t)255;
    return p;
  };
  // persistent across the whole launch:
  unsigned short* wqkv_t = (unsigned short*)alloc((size_t)QKV_N * E_DIM * 2);  // 25.2 MB
  unsigned short* wo_t   = (unsigned short*)alloc((size_t)E_DIM * E_DIM * 2);  //  8.4 MB
  unsigned short* w1_t   = (unsigned short*)alloc((size_t)PD * E_DIM * 2);     // 33.6 MB
  unsigned short* w2_t   = (unsigned short*)alloc((size_t)E_DIM * PD * 2);     // 33.6 MB
  float*          qkvb   = (float*)alloc((size_t)QKV_N * 4);
  float*          hbuf   = (float*)alloc((size_t)M_ROWS * E_DIM * 4);          // 33.6 MB
  // aliased region A: xn[4096x2048 bf16] + qkv[4096x6144 bf16]  ==  g[4096x8192 bf16]
  unsigned short* xn     = (unsigned short*)alloc((size_t)M_ROWS * (E_DIM + QKV_N) * 2);
  unsigned short* qkv    = xn + (size_t)M_ROWS * E_DIM;
  unsigned short* g      = xn;   // reused after qkv's last read (attn kernel)
  // aliased region B: attn[4096x2048 bf16] reused as hn after O-proj reads it
  unsigned short* attn   = (unsigned short*)alloc((size_t)M_ROWS * E_DIM * 2); // 16.8 MB
  unsigned short* hn     = attn; // reused after O-proj
  // peak ws ≈ 218 MB

  // weights -> bf16, transposed to [N][K]
  tconv_kernel<<<dim3(E_DIM / 64, E_DIM / 64), 256, 0, stream>>>(wq, wqkv_t, E_DIM, E_DIM);
  tconv_kernel<<<dim3(E_DIM / 64, E_DIM / 64), 256, 0, stream>>>(wk, wqkv_t + (size_t)E_DIM * E_DIM, E_DIM, E_DIM);
  tconv_kernel<<<dim3(E_DIM / 64, E_DIM / 64), 256, 0, stream>>>(wv, wqkv_t + (size_t)2 * E_DIM * E_DIM, E_DIM, E_DIM);
  tconv_kernel<<<dim3(E_DIM / 64, E_DIM / 64), 256, 0, stream>>>(wo, wo_t, E_DIM, E_DIM);
  tconv_kernel<<<dim3(PD / 64, E_DIM / 64), 256, 0, stream>>>(w1, w1_t, E_DIM, PD);
  tconv_kernel<<<dim3(E_DIM / 64, PD / 64), 256, 0, stream>>>(w2, w2_t, PD, E_DIM);
  concat3_kernel<<<dim3(E_DIM / 256), 256, 0, stream>>>(bq, bk, bv, qkvb);

  // LN1 -> QKV GEMM -> attention
  ln_kernel<<<dim3(M_ROWS), 256, 0, stream>>>(x, ln1w, ln1b, xn);
  gemm_kernel<0, 0, 1><<<dim3(QKV_N / 128, M_ROWS / 128), 256, 0, stream>>>(
      xn, wqkv_t, qkvb, nullptr, qkv, M_ROWS, QKV_N, E_DIM);
  attn_kernel<<<dim3(NQT / 2, BATCH * NH), 256, 0, stream>>>(qkv, attn);

  // O-proj + residual(x) -> h (fp32)
  gemm_kernel<0, 1, 0><<<dim3(E_DIM / 128, M_ROWS / 128), 256, 0, stream>>>(
      attn, wo_t, bo, x, hbuf, M_ROWS, E_DIM, E_DIM);
  // LN2 -> hn (overwrites attn buffer; attn is dead now)
  ln_kernel<<<dim3(M_ROWS), 256, 0, stream>>>(hbuf, ln2w, ln2b, hn);
  // MLP1 + gelu -> g (overwrites xn+qkv region; both dead now)
  gemm_kernel<1, 0, 1><<<dim3(PD / 128, M_ROWS / 128), 256, 0, stream>>>(
      hn, w1_t, b1, nullptr, g, M_ROWS, PD, E_DIM);
  // MLP2 + residual(h) -> out (fp32)
  gemm_kernel<0, 1, 0><<<dim3(E_DIM / 128, M_ROWS / 128), 256, 0, stream>>>(
      g, w2_t, b2, hbuf, (float*)d_out, M_ROWS, E_DIM, PD);
}

// Round 5
// 971.697 us; speedup vs baseline: 1.2761x; 1.0202x over previous
//
#include <hip/hip_runtime.h>

#define E_DIM 2048
#define SEQ 2048
#define BATCH 2
#define NH 16
#define HD 128
#define PD 8192
#define M_ROWS 4096            // BATCH*SEQ
#define QKV_N 6144             // 3*E_DIM
#define NQT 32                 // SEQ/64

typedef __attribute__((ext_vector_type(8))) short bf16x8;
typedef __attribute__((ext_vector_type(4))) float f32x4;

__device__ __forceinline__ unsigned short f2bf(float f) {
  unsigned u = __float_as_uint(f);
  u += 0x7fffu + ((u >> 16) & 1u);
  return (unsigned short)(u >> 16);
}

__device__ __forceinline__ float gelu_f(float x) {
  const float c = 0.7978845608028654f;  // sqrt(2/pi), jax approximate=True
  return 0.5f * x * (1.0f + tanhf(c * (x + 0.044715f * x * x * x)));
}

// async global->LDS, 16B per lane; LDS dest is wave-uniform base + lane*16
#define GLD16(gsrc, ldst) __builtin_amdgcn_global_load_lds( \
    (const __attribute__((address_space(1))) void*)(gsrc),  \
    (__attribute__((address_space(3))) void*)(ldst), 16, 0, 0)

// ---------------------------------------------------------------------------
// LayerNorm: fp32 [rows][2048] -> bf16, applies weight/bias. 1 block per row.
// ---------------------------------------------------------------------------
__global__ __launch_bounds__(256) void ln_kernel(const float* __restrict__ x,
                                                 const float* __restrict__ w,
                                                 const float* __restrict__ b,
                                                 unsigned short* __restrict__ out) {
  const int row = blockIdx.x;
  const int tid = threadIdx.x;
  const float* xr = x + (size_t)row * E_DIM;
  float4 v0 = *(const float4*)(xr + tid * 8);
  float4 v1 = *(const float4*)(xr + tid * 8 + 4);
  float s = v0.x + v0.y + v0.z + v0.w + v1.x + v1.y + v1.z + v1.w;
  float q = v0.x * v0.x + v0.y * v0.y + v0.z * v0.z + v0.w * v0.w +
            v1.x * v1.x + v1.y * v1.y + v1.z * v1.z + v1.w * v1.w;
#pragma unroll
  for (int o = 32; o; o >>= 1) { s += __shfl_xor(s, o); q += __shfl_xor(q, o); }
  __shared__ float ls[8];
  const int lane = tid & 63, wv = tid >> 6;
  if (lane == 0) { ls[wv] = s; ls[4 + wv] = q; }
  __syncthreads();
  s = ls[0] + ls[1] + ls[2] + ls[3];
  q = ls[4] + ls[5] + ls[6] + ls[7];
  const float mu = s * (1.0f / E_DIM);
  const float var = q * (1.0f / E_DIM) - mu * mu;
  const float rstd = rsqrtf(var + 1e-5f);
  float4 w0 = *(const float4*)(w + tid * 8);
  float4 w1 = *(const float4*)(w + tid * 8 + 4);
  float4 b0 = *(const float4*)(b + tid * 8);
  float4 b1 = *(const float4*)(b + tid * 8 + 4);
  ushort4 o0, o1;
  o0.x = f2bf((v0.x - mu) * rstd * w0.x + b0.x);
  o0.y = f2bf((v0.y - mu) * rstd * w0.y + b0.y);
  o0.z = f2bf((v0.z - mu) * rstd * w0.z + b0.z);
  o0.w = f2bf((v0.w - mu) * rstd * w0.w + b0.w);
  o1.x = f2bf((v1.x - mu) * rstd * w1.x + b1.x);
  o1.y = f2bf((v1.y - mu) * rstd * w1.y + b1.y);
  o1.z = f2bf((v1.z - mu) * rstd * w1.z + b1.z);
  o1.w = f2bf((v1.w - mu) * rstd * w1.w + b1.w);
  *(ushort4*)(out + (size_t)row * E_DIM + tid * 8) = o0;
  *(ushort4*)(out + (size_t)row * E_DIM + tid * 8 + 4) = o1;
}

// ---------------------------------------------------------------------------
// Transpose-convert: fp32 in[K][N] -> bf16 out[N][K].  64x64 tiles.
// ---------------------------------------------------------------------------
__global__ __launch_bounds__(256) void tconv_kernel(const float* __restrict__ in,
                                                    unsigned short* __restrict__ out,
                                                    int K, int N) {
  __shared__ float t[64][65];
  const int bn = blockIdx.x, bk = blockIdx.y;
  const int tid = threadIdx.x;
  const int c4 = (tid & 15) * 4;
  const int r0 = tid >> 4;
#pragma unroll
  for (int p = 0; p < 4; ++p) {
    const int r = p * 16 + r0;
    const float4 v = *(const float4*)(in + (size_t)(bk * 64 + r) * N + bn * 64 + c4);
    t[r][c4] = v.x; t[r][c4 + 1] = v.y; t[r][c4 + 2] = v.z; t[r][c4 + 3] = v.w;
  }
  __syncthreads();
#pragma unroll
  for (int p = 0; p < 4; ++p) {
    const int rn = p * 16 + r0;
    ushort4 o;
    o.x = f2bf(t[c4][rn]);     o.y = f2bf(t[c4 + 1][rn]);
    o.z = f2bf(t[c4 + 2][rn]); o.w = f2bf(t[c4 + 3][rn]);
    *(ushort4*)(out + (size_t)(bn * 64 + rn) * K + bk * 64 + c4) = o;
  }
}

__global__ void concat3_kernel(const float* __restrict__ a, const float* __restrict__ b,
                               const float* __restrict__ c, float* __restrict__ o) {
  int i = blockIdx.x * 256 + threadIdx.x;
  if (i < E_DIM) { o[i] = a[i]; o[E_DIM + i] = b[i]; o[2 * E_DIM + i] = c[i]; }
}

// ---------------------------------------------------------------------------
// 256x256 8-phase GEMM (m201 template, plain HIP): C[M,N] = A@Bt^T + bias
// BK=64, 8 waves (2Mx4N), dbuf LDS 128KiB, T2 swizzle, T5 setprio, T1 XCD.
// ---------------------------------------------------------------------------
#define STAGE_A(d, kt) do {                                                   \
  const unsigned short* Ab_ = A + (size_t)(br * 256) * K + (size_t)(kt) * 64 + srcCh * 8; \
  _Pragma("unroll") for (int j_ = 0; j_ < 4; ++j_)                            \
    GLD16(Ab_ + (size_t)(j_ * 64 + (tid >> 3)) * K,                           \
          smem + (d) * 65536 + j_ * 8192 + wid * 1024);                       \
} while (0)

#define STAGE_B(d, kt) do {                                                   \
  const unsigned short* Bb_ = Bt + (size_t)(bc * 256) * K + (size_t)(kt) * 64 + srcCh * 8; \
  _Pragma("unroll") for (int j_ = 0; j_ < 4; ++j_)                            \
    GLD16(Bb_ + (size_t)(j_ * 64 + (tid >> 3)) * K,                           \
          smem + (d) * 65536 + 32768 + j_ * 8192 + wid * 1024);               \
} while (0)

#define LDA_Q(d, mh) do {                                                     \
  const char* ab_ = smem + (d) * 65536;                                       \
  _Pragma("unroll") for (int mf_ = 0; mf_ < 4; ++mf_) {                       \
    const int row_ = wm * 128 + (mh) * 64 + mf_ * 16 + (lane & 15);           \
    _Pragma("unroll") for (int ks_ = 0; ks_ < 2; ++ks_) {                     \
      const int ch_ = (ks_ * 4 + (lane >> 4)) ^ (row_ & 7);                   \
      aq[mf_ * 2 + ks_] = *(const bf16x8*)(ab_ + row_ * 128 + ch_ * 16);      \
    } }                                                                       \
} while (0)

#define LDB_Q(d, nh, bq) do {                                                 \
  const char* bb_ = smem + (d) * 65536 + 32768;                               \
  _Pragma("unroll") for (int nf_ = 0; nf_ < 2; ++nf_) {                       \
    const int row_ = wn * 64 + (nh) * 32 + nf_ * 16 + (lane & 15);            \
    _Pragma("unroll") for (int ks_ = 0; ks_ < 2; ++ks_) {                     \
      const int ch_ = (ks_ * 4 + (lane >> 4)) ^ (row_ & 7);                   \
      bq[nf_ * 2 + ks_] = *(const bf16x8*)(bb_ + row_ * 128 + ch_ * 16);      \
    } }                                                                       \
} while (0)

#define MMQ(mh, nh, bq) do {                                                  \
  __builtin_amdgcn_s_setprio(1);                                              \
  _Pragma("unroll") for (int mf_ = 0; mf_ < 4; ++mf_)                         \
  _Pragma("unroll") for (int nf_ = 0; nf_ < 2; ++nf_)                         \
  _Pragma("unroll") for (int ks_ = 0; ks_ < 2; ++ks_)                         \
    acc[(mh) * 4 + mf_][(nh) * 2 + nf_] = __builtin_amdgcn_mfma_f32_16x16x32_bf16( \
        aq[mf_ * 2 + ks_], bq[nf_ * 2 + ks_], acc[(mh) * 4 + mf_][(nh) * 2 + nf_], 0, 0, 0); \
  __builtin_amdgcn_s_setprio(0);                                              \
} while (0)

template <int ACT, int RES, int OUTBF>
__global__ __launch_bounds__(512, 2) void gemm256_kernel(
    const unsigned short* __restrict__ A, const unsigned short* __restrict__ Bt,
    const float* __restrict__ bias, const float* __restrict__ res,
    void* __restrict__ Cout, int M, int N, int K, int nbc) {
  extern __shared__ char smem[];   // 2 x (A 32KB | B 32KB) = 128 KiB
  const int tid = threadIdx.x, lane = tid & 63, wid = tid >> 6;
  const int wm = wid >> 2, wn = wid & 3;
  // T1: bijective XCD swizzle (gridDim.x % 8 == 0)
  const int cpx = gridDim.x >> 3;
  const int bid = (blockIdx.x & 7) * cpx + (blockIdx.x >> 3);
  const int br = bid / nbc, bc = bid % nbc;
  // T2 stage-source pre-swizzle: chunk ^= (row&7); independent of j here.
  const int srcCh = (tid & 7) ^ ((tid >> 3) & 7);

  f32x4 acc[8][4] = {};
  bf16x8 aq[8], bq0[4], bq1[4];

  const int NT = K >> 6;
  STAGE_A(0, 0);
  STAGE_B(0, 0);
  for (int t = 0; t < NT; ++t) {
    const int cur = t & 1;
    const bool pf = (t + 1 < NT);
    __syncthreads();               // vmcnt(0)+lgkmcnt(0) drain: tile t resident
    // ---- ph0: A(mh0)+B(nh0) reads; stage next A ----
    LDA_Q(cur, 0);
    LDB_Q(cur, 0, bq0);
    if (pf) STAGE_A(cur ^ 1, t + 1);
    __builtin_amdgcn_s_barrier();
    MMQ(0, 0, bq0);
    __builtin_amdgcn_s_barrier();
    // ---- ph1: B(nh1) reads; stage next B ----
    LDB_Q(cur, 1, bq1);
    if (pf) STAGE_B(cur ^ 1, t + 1);
    __builtin_amdgcn_s_barrier();
    MMQ(0, 1, bq1);
    __builtin_amdgcn_s_barrier();
    // ---- ph2: A(mh1) reads ----
    LDA_Q(cur, 1);
    __builtin_amdgcn_s_barrier();
    MMQ(1, 1, bq1);
    __builtin_amdgcn_s_barrier();
    // ---- ph3: B(nh0) reads ----
    LDB_Q(cur, 0, bq0);
    __builtin_amdgcn_s_barrier();
    MMQ(1, 0, bq0);
    // trailing barrier is next iter's __syncthreads
  }

  // ---- epilogue ----
#pragma unroll
  for (int nfg = 0; nfg < 4; ++nfg) {
    const int col = bc * 256 + wn * 64 + nfg * 16 + (lane & 15);
    const float bv = bias[col];
#pragma unroll
    for (int mfg = 0; mfg < 8; ++mfg) {
      const int row0 = br * 256 + wm * 128 + mfg * 16 + (lane >> 4) * 4;
#pragma unroll
      for (int r = 0; r < 4; ++r) {
        const size_t idx = (size_t)(row0 + r) * N + col;
        float v = acc[mfg][nfg][r] + bv;
        if (RES) v += res[idx];
        if (ACT) v = gelu_f(v);
        if (OUTBF) ((unsigned short*)Cout)[idx] = f2bf(v);
        else       ((float*)Cout)[idx] = v;
      }
    }
  }
}

// ---------------------------------------------------------------------------
// Causal flash attention, depth-1 pipelined. qkv bf16 [4096][6144] (Q|K|V).
// Block: 1 (b,h) x 2 paired q-tiles (qt, 31-qt) -> equal work (33 iters).
// ---------------------------------------------------------------------------
__global__ __launch_bounds__(256) void attn_kernel(const unsigned short* __restrict__ qkv,
                                                   unsigned short* __restrict__ out) {
  __shared__ unsigned short lsK[2][64 * 128];  // [key][d], chunk ^= (key&7)
  __shared__ unsigned short lsV[128 * 64];     // Vt [d][key], chunk ^= (d&7)^((d>>3)&7)
  __shared__ unsigned short lsP[4 * 1024];     // per-wave P [16][64], chunk ^= (qrow&7)
  const int tid = threadIdx.x, lane = tid & 63, w = tid >> 6;
  const int pair = blockIdx.x, bh = blockIdx.y;
  const int b = bh >> 4, h = bh & 15;
  const size_t base = (size_t)b * SEQ * QKV_N + h * HD;
  const float scale = 0.08838834764831845f;  // 1/sqrt(128)
  char* lsPw = (char*)(lsP + w * 1024);
  const int vdc = tid & 15, vkr = tid >> 4;

  for (int half = 0; half < 2; ++half) {
    const int qt = half ? (NQT - 1 - pair) : pair;
    const int q0 = qt * 64;
    const int nt = qt + 1;

    bf16x8 qf[4];
    {
      const unsigned short* qp =
          qkv + base + (size_t)(q0 + w * 16 + (lane & 15)) * QKV_N + (lane >> 4) * 8;
#pragma unroll
      for (int kk = 0; kk < 4; ++kk) qf[kk] = *(const bf16x8*)(qp + kk * 32);
    }
    f32x4 o_acc[8] = {};
    float m_r[4] = {-INFINITY, -INFINITY, -INFINITY, -INFINITY};
    float l_r[4] = {0.f, 0.f, 0.f, 0.f};
    bf16x8 vv0, vv1, vv2, vv3;

    {
#pragma unroll
      for (int i = 0; i < 4; ++i) {
        const int row = (i * 4 + w) * 4 + (lane >> 4);
        const int cs = (lane & 15) ^ (row & 7);
        GLD16(qkv + base + E_DIM + (size_t)row * QKV_N + cs * 8,
              (char*)lsK[0] + (i * 4 + w) * 1024);
      }
      const unsigned short* gv = qkv + base + 2 * E_DIM + (size_t)(vkr * 4) * QKV_N + vdc * 8;
      vv0 = *(const bf16x8*)(gv);
      vv1 = *(const bf16x8*)(gv + QKV_N);
      vv2 = *(const bf16x8*)(gv + 2 * QKV_N);
      vv3 = *(const bf16x8*)(gv + 3 * QKV_N);
    }
    __syncthreads();
#pragma unroll
    for (int e = 0; e < 8; ++e) {
      const int d = vdc * 8 + e;
      const int swz = (d & 7) ^ ((d >> 3) & 7);
      {
        const int k = vkr * 4;
        const int off = d * 128 + (((k >> 3) ^ swz) << 4) + (k & 7) * 2;
        ushort2 t2; t2.x = (unsigned short)vv0[e]; t2.y = (unsigned short)vv1[e];
        *(ushort2*)((char*)lsV + off) = t2;
      }
      {
        const int k = vkr * 4 + 2;
        const int off = d * 128 + (((k >> 3) ^ swz) << 4) + (k & 7) * 2;
        ushort2 t2; t2.x = (unsigned short)vv2[e]; t2.y = (unsigned short)vv3[e];
        *(ushort2*)((char*)lsV + off) = t2;
      }
    }

    for (int kt = 0; kt < nt; ++kt) {
      const int cur = kt & 1;
      const bool pf = (kt + 1 < nt);
      if (pf) {
        const int k0n = (kt + 1) * 64;
#pragma unroll
        for (int i = 0; i < 4; ++i) {
          const int row = (i * 4 + w) * 4 + (lane >> 4);
          const int cs = (lane & 15) ^ (row & 7);
          GLD16(qkv + base + E_DIM + (size_t)(k0n + row) * QKV_N + cs * 8,
                (char*)lsK[cur ^ 1] + (i * 4 + w) * 1024);
        }
        const unsigned short* gv =
            qkv + base + 2 * E_DIM + (size_t)(k0n + vkr * 4) * QKV_N + vdc * 8;
        vv0 = *(const bf16x8*)(gv);
        vv1 = *(const bf16x8*)(gv + QKV_N);
        vv2 = *(const bf16x8*)(gv + 2 * QKV_N);
        vv3 = *(const bf16x8*)(gv + 3 * QKV_N);
      }
      f32x4 sacc[4] = {};
#pragma unroll
      for (int kk = 0; kk < 4; ++kk) {
#pragma unroll
        for (int n = 0; n < 4; ++n) {
          const int row = n * 16 + (lane & 15);
          const int ch = (kk * 4 + (lane >> 4)) ^ (row & 7);
          bf16x8 kf = *(const bf16x8*)((const char*)lsK[cur] + row * 256 + ch * 16);
          sacc[n] = __builtin_amdgcn_mfma_f32_16x16x32_bf16(qf[kk], kf, sacc[n], 0, 0, 0);
        }
      }
      const bool diag = (kt == nt - 1);
      float p[4][4];
#pragma unroll
      for (int r = 0; r < 4; ++r) {
        float sv[4];
#pragma unroll
        for (int n = 0; n < 4; ++n) {
          float t = sacc[n][r] * scale;
          if (diag && (n * 16 + (lane & 15)) > (w * 16 + (lane >> 4) * 4 + r)) t = -INFINITY;
          sv[n] = t;
        }
        float tm = fmaxf(fmaxf(sv[0], sv[1]), fmaxf(sv[2], sv[3]));
        tm = fmaxf(tm, __shfl_xor(tm, 1));
        tm = fmaxf(tm, __shfl_xor(tm, 2));
        tm = fmaxf(tm, __shfl_xor(tm, 4));
        tm = fmaxf(tm, __shfl_xor(tm, 8));
        const float mn = fmaxf(m_r[r], tm);
        const float corr = __expf(m_r[r] - mn);
        float ps = 0.f;
#pragma unroll
        for (int n = 0; n < 4; ++n) { p[n][r] = __expf(sv[n] - mn); ps += p[n][r]; }
        ps += __shfl_xor(ps, 1); ps += __shfl_xor(ps, 2);
        ps += __shfl_xor(ps, 4); ps += __shfl_xor(ps, 8);
        l_r[r] = l_r[r] * corr + ps;
        m_r[r] = mn;
#pragma unroll
        for (int dn = 0; dn < 8; ++dn) o_acc[dn][r] *= corr;
      }
      __syncthreads();
#pragma unroll
      for (int n = 0; n < 4; ++n)
#pragma unroll
        for (int r = 0; r < 4; ++r) {
          const int prow = (lane >> 4) * 4 + r;
          const int pcol = n * 16 + (lane & 15);
          const int off = prow * 128 + ((((pcol >> 3) ^ (prow & 7))) << 4) + (pcol & 7) * 2;
          *(unsigned short*)(lsPw + off) = f2bf(p[n][r]);
        }
      bf16x8 pa[2];
#pragma unroll
      for (int ks = 0; ks < 2; ++ks) {
        const int prow = lane & 15;
        const int ch = (ks * 4 + (lane >> 4)) ^ (prow & 7);
        pa[ks] = *(const bf16x8*)(lsPw + prow * 128 + ch * 16);
      }
#pragma unroll
      for (int dn = 0; dn < 8; ++dn)
#pragma unroll
        for (int ks = 0; ks < 2; ++ks) {
          const int d = dn * 16 + (lane & 15);
          const int ch = (ks * 4 + (lane >> 4)) ^ (d & 7) ^ ((d >> 3) & 7);
          bf16x8 vf = *(const bf16x8*)((const char*)lsV + d * 128 + ch * 16);
          o_acc[dn] = __builtin_amdgcn_mfma_f32_16x16x32_bf16(pa[ks], vf, o_acc[dn], 0, 0, 0);
        }
      __syncthreads();
      if (pf) {
#pragma unroll
        for (int e = 0; e < 8; ++e) {
          const int d = vdc * 8 + e;
          const int swz = (d & 7) ^ ((d >> 3) & 7);
          {
            const int k = vkr * 4;
            const int off = d * 128 + (((k >> 3) ^ swz) << 4) + (k & 7) * 2;
            ushort2 t2; t2.x = (unsigned short)vv0[e]; t2.y = (unsigned short)vv1[e];
            *(ushort2*)((char*)lsV + off) = t2;
          }
          {
            const int k = vkr * 4 + 2;
            const int off = d * 128 + (((k >> 3) ^ swz) << 4) + (k & 7) * 2;
            ushort2 t2; t2.x = (unsigned short)vv2[e]; t2.y = (unsigned short)vv3[e];
            *(ushort2*)((char*)lsV + off) = t2;
          }
        }
      }
    }
#pragma unroll
    for (int r = 0; r < 4; ++r) {
      const float inv = 1.0f / l_r[r];
      const int row = q0 + w * 16 + (lane >> 4) * 4 + r;
      unsigned short* op = out + ((size_t)(b * SEQ + row)) * E_DIM + h * HD + (lane & 15);
#pragma unroll
      for (int dn = 0; dn < 8; ++dn) op[dn * 16] = f2bf(o_acc[dn][r] * inv);
    }
  }
}

// ---------------------------------------------------------------------------
extern "C" void kernel_launch(void* const* d_in, const int* in_sizes, int n_in,
                              void* d_out, int out_size, void* d_ws, size_t ws_size,
                              hipStream_t stream) {
  const float* x    = (const float*)d_in[0];
  const float* ln1w = (const float*)d_in[1];
  const float* ln1b = (const float*)d_in[2];
  const float* ln2w = (const float*)d_in[3];
  const float* ln2b = (const float*)d_in[4];
  const float* wq   = (const float*)d_in[5];
  const float* bq   = (const float*)d_in[6];
  const float* wk   = (const float*)d_in[7];
  const float* bk   = (const float*)d_in[8];
  const float* wv   = (const float*)d_in[9];
  const float* bv   = (const float*)d_in[10];
  const float* wo   = (const float*)d_in[11];
  const float* bo   = (const float*)d_in[12];
  const float* w1   = (const float*)d_in[13];
  const float* b1   = (const float*)d_in[14];
  const float* w2   = (const float*)d_in[15];
  const float* b2   = (const float*)d_in[16];
  (void)in_sizes; (void)n_in; (void)out_size; (void)ws_size;

  char* ws = (char*)d_ws;
  size_t off = 0;
  auto alloc = [&](size_t bytes) {
    char* p = ws + off;
    off += (bytes + 255) & ~(size_t)255;
    return p;
  };
  unsigned short* wqkv_t = (unsigned short*)alloc((size_t)QKV_N * E_DIM * 2);
  unsigned short* wo_t   = (unsigned short*)alloc((size_t)E_DIM * E_DIM * 2);
  unsigned short* w1_t   = (unsigned short*)alloc((size_t)PD * E_DIM * 2);
  unsigned short* w2_t   = (unsigned short*)alloc((size_t)E_DIM * PD * 2);
  float*          qkvb   = (float*)alloc((size_t)QKV_N * 4);
  float*          hbuf   = (float*)alloc((size_t)M_ROWS * E_DIM * 4);
  unsigned short* xn     = (unsigned short*)alloc((size_t)M_ROWS * (E_DIM + QKV_N) * 2);
  unsigned short* qkv    = xn + (size_t)M_ROWS * E_DIM;
  unsigned short* g      = xn;   // reused after qkv's last read (attn kernel)
  unsigned short* attn   = (unsigned short*)alloc((size_t)M_ROWS * E_DIM * 2);
  unsigned short* hn     = attn; // reused after O-proj

  // allow 128 KiB dynamic LDS on the 8-phase GEMM instantiations
  hipFuncSetAttribute((const void*)gemm256_kernel<0, 0, 1>,
                      hipFuncAttributeMaxDynamicSharedMemorySize, 131072);
  hipFuncSetAttribute((const void*)gemm256_kernel<0, 1, 0>,
                      hipFuncAttributeMaxDynamicSharedMemorySize, 131072);
  hipFuncSetAttribute((const void*)gemm256_kernel<1, 0, 1>,
                      hipFuncAttributeMaxDynamicSharedMemorySize, 131072);

  // weights -> bf16, transposed to [N][K]
  tconv_kernel<<<dim3(E_DIM / 64, E_DIM / 64), 256, 0, stream>>>(wq, wqkv_t, E_DIM, E_DIM);
  tconv_kernel<<<dim3(E_DIM / 64, E_DIM / 64), 256, 0, stream>>>(wk, wqkv_t + (size_t)E_DIM * E_DIM, E_DIM, E_DIM);
  tconv_kernel<<<dim3(E_DIM / 64, E_DIM / 64), 256, 0, stream>>>(wv, wqkv_t + (size_t)2 * E_DIM * E_DIM, E_DIM, E_DIM);
  tconv_kernel<<<dim3(E_DIM / 64, E_DIM / 64), 256, 0, stream>>>(wo, wo_t, E_DIM, E_DIM);
  tconv_kernel<<<dim3(PD / 64, E_DIM / 64), 256, 0, stream>>>(w1, w1_t, E_DIM, PD);
  tconv_kernel<<<dim3(E_DIM / 64, PD / 64), 256, 0, stream>>>(w2, w2_t, PD, E_DIM);
  concat3_kernel<<<dim3(E_DIM / 256), 256, 0, stream>>>(bq, bk, bv, qkvb);

  // LN1 -> QKV GEMM -> attention
  ln_kernel<<<dim3(M_ROWS), 256, 0, stream>>>(x, ln1w, ln1b, xn);
  gemm256_kernel<0, 0, 1><<<dim3((M_ROWS / 256) * (QKV_N / 256)), 512, 131072, stream>>>(
      xn, wqkv_t, qkvb, nullptr, qkv, M_ROWS, QKV_N, E_DIM, QKV_N / 256);
  attn_kernel<<<dim3(NQT / 2, BATCH * NH), 256, 0, stream>>>(qkv, attn);

  // O-proj + residual(x) -> h (fp32)
  gemm256_kernel<0, 1, 0><<<dim3((M_ROWS / 256) * (E_DIM / 256)), 512, 131072, stream>>>(
      attn, wo_t, bo, x, hbuf, M_ROWS, E_DIM, E_DIM, E_DIM / 256);
  // LN2 -> hn (overwrites attn buffer)
  ln_kernel<<<dim3(M_ROWS), 256, 0, stream>>>(hbuf, ln2w, ln2b, hn);
  // MLP1 + gelu -> g (overwrites xn+qkv region)
  gemm256_kernel<1, 0, 1><<<dim3((M_ROWS / 256) * (PD / 256)), 512, 131072, stream>>>(
      hn, w1_t, b1, nullptr, g, M_ROWS, PD, E_DIM, PD / 256);
  // MLP2 + residual(h) -> out (fp32)
  gemm256_kernel<0, 1, 0><<<dim3((M_ROWS / 256) * (E_DIM / 256)), 512, 131072, stream>>>(
      g, w2_t, b2, hbuf, (float*)d_out, M_ROWS, E_DIM, PD, E_DIM / 256);
}